// Round 5
// baseline (457.286 us; speedup 1.0000x reference)
//
#include <hip/hip_runtime.h>
#include <math.h>

#define NB_B 65536
#define NL   512
#define NP   96
#define NE   16
#define NEL  14
#define NF   256
#define TEMP_INV (1.0f/0.07f)
#define TAU  1e-5f
#define PI_D 3.14159265358979323846

typedef __attribute__((ext_vector_type(8))) short bf16x8;
typedef __attribute__((ext_vector_type(4))) float f32x4;

// ---------------- workspace layout (bytes) ----------------
// 0        pcnt[256]   padded stride 64B (pair counts)
// 16384    ptk[256]    padded stride 64B (scatter tickets)
// 32768    pbase[256]  (exclusive scan of pcnt)
// 33792    flagcnt
// 33856    flaglist[65536]
// 296000   Ssum[14*96]
// 301376   WgT[256*16]
// 317760   bgT[16]
// 317824   twf[256]  float2
// 319872   twd[512]  double2
// 328064   rec[65536]  int: pid = i0*16+i1
// 590208   hdr[65536]  float4: mu, sd, last, w0
// 1638784  ridx[65536] int (compact pair-bucketed row list)
// 1900928  Wrb[16*96*512] bf16 (experts 14,15 zero-filled)
// total ~3.5 MB

#define WS_PCNT     0
#define WS_PTK      16384
#define WS_PBASE    32768
#define WS_FLAGCNT  33792
#define WS_FLAG     33856
#define WS_SSUM     296000
#define WS_WGT      301376
#define WS_BGT      317760
#define WS_TWF      317824
#define WS_TWD      319872
#define WS_REC      328064
#define WS_HDR      590208
#define WS_RIDX     1638784
#define WS_WRB      1900928

__device__ __forceinline__ unsigned short f2bf(float f) {
    unsigned u = __float_as_uint(f);
    unsigned r = (u + 0x7fffu + ((u >> 16) & 1u)) >> 16;
    return (unsigned short)r;
}

__global__ __launch_bounds__(256) void k_prep(
    const float* __restrict__ Wg, const float* __restrict__ bg,
    const float* __restrict__ Wr,
    float* __restrict__ Ssum, float* __restrict__ WgT, float* __restrict__ bgT,
    float2* __restrict__ twf, double2* __restrict__ twd,
    int* __restrict__ pcnt, int* __restrict__ flagcnt)
{
    int g = blockIdx.x * 256 + threadIdx.x;
    if (g < NEL * NP) {
        const float4* w = (const float4*)(Wr + (size_t)g * NL);
        float s = 0.f;
        for (int i = 0; i < NL / 4; i++) { float4 v = w[i]; s += v.x + v.y + v.z + v.w; }
        Ssum[g] = s;
    }
    if (g < NF * NE) {
        int f = g >> 4, e = g & 15;
        WgT[g] = Wg[e * NF + f] * TEMP_INV;
    }
    if (g < NF) {
        double a = -2.0 * PI_D * (double)g / 512.0;
        twf[g] = make_float2((float)cos(a), (float)sin(a));
    }
    if (g < 512) {
        double a = -2.0 * PI_D * (double)g / 512.0;
        twd[g] = make_double2(cos(a), sin(a));
    }
    if (g < 256) pcnt[g << 4] = 0;
    if (g < NE) bgT[g] = bg[g] * TEMP_INV;
    if (g == 300) *flagcnt = 0;
}

// Wr f32 -> bf16 (RNE); experts 14,15 zero-filled. 768 blocks.
__global__ __launch_bounds__(256) void k_cvt(
    const float4* __restrict__ Wr, ushort4* __restrict__ Wrb)
{
    int g = blockIdx.x * 256 + threadIdx.x;          // < 196608
    ushort4 o = make_ushort4(0, 0, 0, 0);
    if (g < NEL * NP * NL / 4) {
        float4 v = Wr[g];
        o.x = f2bf(v.x); o.y = f2bf(v.y); o.z = f2bf(v.z); o.w = f2bf(v.w);
    }
    Wrb[g] = o;
}

// Pack-2 real FFT per wave: rows (2w,2w+1) as z=a+ib, one 512-pt complex FFT,
// conjugate-symmetry split. Emits per-row header (mu,sd,last,w0) + pair id.
__global__ __launch_bounds__(256) void k_gate(
    const float* __restrict__ x,
    const float* __restrict__ WgT, const float* __restrict__ bgT,
    const float2* __restrict__ twf,
    int* __restrict__ rec, float4* __restrict__ hdr,
    int* __restrict__ flaglist, int* __restrict__ flagcnt)
{
    __shared__ float2 s_tw[256];
    __shared__ float2 s_z[4][576];      // Z by register-order idx i+(i>>3)
    __shared__ float  s_g[4][2][16];
    float* s_Iv = (float*)&s_z[0][0];   // alias: I after Z consumed (barrier-sep)

    const int t = threadIdx.x;
    const int wv = t >> 6, l = t & 63;
    const int b0 = blockIdx.x * 8 + wv * 2;
    s_tw[t] = twf[t];

    const float* xa = x + (size_t)b0 * NL;
    const float* xb = xa + NL;
    float xr[8], xi[8];
#pragma unroll
    for (int k = 0; k < 8; k++) { xr[k] = xa[k * 64 + l]; xi[k] = xb[k * 64 + l]; }

    float sa = 0.f, qa = 0.f, sb = 0.f, qb = 0.f;
#pragma unroll
    for (int k = 0; k < 8; k++) {
        sa += xr[k]; qa += xr[k] * xr[k];
        sb += xi[k]; qb += xi[k] * xi[k];
    }
#pragma unroll
    for (int m = 1; m < 64; m <<= 1) {
        sa += __shfl_xor(sa, m); qa += __shfl_xor(qa, m);
        sb += __shfl_xor(sb, m); qb += __shfl_xor(qb, m);
    }
    const float mu_a = sa * (1.f / 512.f);
    const float sd_a = sqrtf(qa * (1.f / 512.f) - mu_a * mu_a + 1e-5f);
    const float mu_b = sb * (1.f / 512.f);
    const float sd_b = sqrtf(qb * (1.f / 512.f) - mu_b * mu_b + 1e-5f);
    const float last_a = __shfl(xr[7], 63);
    const float last_b = __shfl(xi[7], 63);
#pragma unroll
    for (int k = 0; k < 8; k++) { xr[k] -= mu_a; xi[k] -= mu_b; }
    __syncthreads();

    // ---- DIF FFT (complex), natural in, bit-reversed out ----
#pragma unroll
    for (int k = 0; k < 4; k++) {                       // stage 0: half=256
        float2 w = s_tw[k * 64 + l];
        float ur = xr[k], ui = xi[k], vr = xr[k + 4], vi = xi[k + 4];
        xr[k] = ur + vr; xi[k] = ui + vi;
        float dr = ur - vr, di = ui - vi;
        xr[k + 4] = dr * w.x - di * w.y; xi[k + 4] = dr * w.y + di * w.x;
    }
    {                                                   // stage 1: half=128
        const int kk[4] = {0, 1, 4, 5};
#pragma unroll
        for (int g2 = 0; g2 < 4; g2++) {
            int k = kk[g2];
            float2 w = s_tw[((k & 1) * 64 + l) << 1];
            float ur = xr[k], ui = xi[k], vr = xr[k + 2], vi = xi[k + 2];
            xr[k] = ur + vr; xi[k] = ui + vi;
            float dr = ur - vr, di = ui - vi;
            xr[k + 2] = dr * w.x - di * w.y; xi[k + 2] = dr * w.y + di * w.x;
        }
    }
    {                                                   // stage 2: half=64
        float2 w = s_tw[l << 2];
#pragma unroll
        for (int k = 0; k < 8; k += 2) {
            float ur = xr[k], ui = xi[k], vr = xr[k + 1], vi = xi[k + 1];
            xr[k] = ur + vr; xi[k] = ui + vi;
            float dr = ur - vr, di = ui - vi;
            xr[k + 1] = dr * w.x - di * w.y; xi[k + 1] = dr * w.y + di * w.x;
        }
    }
#pragma unroll
    for (int st = 3; st < 9; st++) {                    // stages 3..8 cross-lane
        const int half = 256 >> st;
        const int tt = (l & (half - 1)) << st;
        float2 w = s_tw[tt];
        const bool up = (l & half) != 0;
        const float cc = up ? w.x : 1.f;
        const float ss = up ? w.y : 0.f;
#pragma unroll
        for (int k = 0; k < 8; k++) {
            float pr = __shfl_xor(xr[k], half);
            float pi = __shfl_xor(xi[k], half);
            float ar = up ? (pr - xr[k]) : (xr[k] + pr);
            float ai = up ? (pi - xi[k]) : (xi[k] + pi);
            xr[k] = ar * cc - ai * ss;
            xi[k] = ar * ss + ai * cc;
        }
    }

#pragma unroll
    for (int k = 0; k < 8; k++) {
        int i = k * 64 + l;
        s_z[wv][i + (i >> 3)] = make_float2(xr[k], xi[k]);
    }
    __syncthreads();

    // conjugate-symmetry split: lane l owns bins f = 4l..4l+3 (x4 scale cancels)
    float Ia[4], Ib[4];
    float psa = 0.f, psb = 0.f;
#pragma unroll
    for (int j = 0; j < 4; j++) {
        int f = (l << 2) | j;
        int i1_ = (int)(__brev((unsigned)f) >> 23);
        int i2_ = (int)(__brev((unsigned)((512 - f) & 511)) >> 23);
        float2 z1 = s_z[wv][i1_ + (i1_ >> 3)];
        float2 z2 = s_z[wv][i2_ + (i2_ >> 3)];
        float pr_ = z1.x + z2.x, qm = z1.y - z2.y;
        float qp = z1.y + z2.y, pm = z1.x - z2.x;
        Ia[j] = pr_ * pr_ + qm * qm;
        Ib[j] = qp * qp + pm * pm;
        psa += Ia[j]; psb += Ib[j];
    }
#pragma unroll
    for (int m = 1; m < 64; m <<= 1) {
        psa += __shfl_xor(psa, m); psb += __shfl_xor(psb, m);
    }
    if (psa == 0.f) psa = 1.f;
    if (psb == 0.f) psb = 1.f;
    const float inv_a = 1.f / psa, inv_b = 1.f / psb;
    __syncthreads();

    float* myI = s_Iv + wv * 1152;
#pragma unroll
    for (int j = 0; j < 4; j++) {
        int f = (l << 2) | j;
        int fi = f + (f >> 3);
        myI[fi] = Ia[j];
        myI[288 + fi] = Ib[j];
    }
    __syncthreads();

    {
        int e = l >> 2, cq = l & 3;
        float acc_a = 0.f, acc_b = 0.f;
#pragma unroll 4
        for (int j = 0; j < 64; j++) {
            int f = cq * 64 + j;
            int fi = f + (f >> 3);
            float wgv = WgT[f * 16 + e];
            acc_a += myI[fi] * wgv;
            acc_b += myI[288 + fi] * wgv;
        }
        acc_a += __shfl_xor(acc_a, 1); acc_a += __shfl_xor(acc_a, 2);
        acc_b += __shfl_xor(acc_b, 1); acc_b += __shfl_xor(acc_b, 2);
        if (cq == 0) {
            s_g[wv][0][e] = acc_a * inv_a + bgT[e];
            s_g[wv][1][e] = acc_b * inv_b + bgT[e];
        }
    }
    __syncthreads();

#pragma unroll
    for (int r = 0; r < 2; r++) {
        if (l == 0) {
            const float mu = r ? mu_b : mu_a;
            const float sd = r ? sd_b : sd_a;
            const float last = r ? last_b : last_a;
            const int b = b0 + r;
            float b0v = -1e30f, b1v = -1e30f, b2v = -1e30f; int i0 = 0, i1 = 0;
            for (int i = 0; i < 16; i++) {
                float v = s_g[wv][r][i];
                if (v > b0v) { b2v = b1v; b1v = b0v; i1 = i0; b0v = v; i0 = i; }
                else if (v > b1v) { b2v = b1v; b1v = v; i1 = i; }
                else if (v > b2v) { b2v = v; }
            }
            float e1 = expf(b1v - b0v);
            float w0 = 1.f / (1.f + e1);
            rec[b] = i0 * 16 + i1;
            hdr[b] = make_float4(mu, sd, last, w0);
            if (b1v - b2v < TAU) {
                int pos = atomicAdd(flagcnt, 1);
                flaglist[pos] = b;
            }
        }
    }
}

// f64 phasor-DFT refinement for flagged (near-tie) rows: rewrites rec + hdr.w.
__global__ __launch_bounds__(256) void k_refine(
    const float* __restrict__ x, const double2* __restrict__ twd,
    const float* __restrict__ Wg, const float* __restrict__ bg,
    int* __restrict__ rec, float4* __restrict__ hdr,
    const int* __restrict__ flaglist, const int* __restrict__ flagcnt)
{
    __shared__ double s_x[512];
    __shared__ double s_I[256];
    __shared__ double s_red[16];
    __shared__ double s_g[16];
    const int nf = *flagcnt;
    const int t = threadIdx.x;
    const int wid = t >> 6, lane = t & 63;
    for (int fi = blockIdx.x; fi < nf; fi += gridDim.x) {
        const int b = flaglist[fi];
        const float* xp = x + (size_t)b * NL;
        double v0 = (double)xp[t], v1 = (double)xp[t + 256];
        double lsum = v0 + v1;
        for (int m = 1; m < 64; m <<= 1) lsum += __shfl_xor(lsum, m);
        if (lane == 0) s_red[wid] = lsum;
        __syncthreads();
        double mu = (s_red[0] + s_red[1] + s_red[2] + s_red[3]) * (1.0 / 512.0);
        s_x[t] = v0 - mu; s_x[t + 256] = v1 - mu;
        __syncthreads();
        double2 w = twd[t];
        double pr = 1.0, pi = 0.0, cr = 0.0, ci = 0.0;
        for (int n = 0; n < 512; n++) {
            double xv = s_x[n];
            cr += xv * pr; ci += xv * pi;
            double t2 = pr * w.x - pi * w.y;
            pi = pr * w.y + pi * w.x;
            pr = t2;
        }
        double I = cr * cr + ci * ci;
        s_I[t] = I;
        double ls = I;
        for (int m = 1; m < 64; m <<= 1) ls += __shfl_xor(ls, m);
        if (lane == 0) s_red[8 + wid] = ls;
        __syncthreads();
        double stot = s_red[8] + s_red[9] + s_red[10] + s_red[11];
        if (stot == 0.0) stot = 1.0;
        if (t < 16) {
            double acc = 0.0;
            const float* wrow = Wg + t * NF;
            for (int f = 0; f < NF; f++) acc += s_I[f] * (double)wrow[f];
            s_g[t] = (acc / stot + (double)bg[t]) * (1.0 / 0.07);
        }
        __syncthreads();
        if (t == 0) {
            double c0 = -1e300, c1 = -1e300; int j0 = 0, j1 = 0;
            for (int i = 0; i < 16; i++) {
                double v = s_g[i];
                if (v > c0) { c1 = c0; j1 = j0; c0 = v; j0 = i; }
                else if (v > c1) { c1 = v; j1 = i; }
            }
            double e1 = exp(c1 - c0);
            float w0f = (float)(1.0 / (1.0 + e1));
            rec[b] = j0 * 16 + j1;
            ((float*)(hdr + b))[3] = w0f;
        }
        __syncthreads();
    }
}

// Pair histogram: LDS hist -> padded global counters.
__global__ __launch_bounds__(256) void k_count(
    const int* __restrict__ rec, int* __restrict__ pcnt)
{
    __shared__ int h[256];
    const int t = threadIdx.x;
    h[t] = 0;
    __syncthreads();
    atomicAdd(&h[rec[blockIdx.x * 256 + t]], 1);
    __syncthreads();
    if (h[t]) atomicAdd(&pcnt[t << 4], h[t]);
}

// Exclusive scan of 256 pair counts -> pbase; init tickets.
__global__ __launch_bounds__(256) void k_scan(
    const int* __restrict__ pcnt, int* __restrict__ pbase, int* __restrict__ ptk)
{
    __shared__ int s[256];
    const int t = threadIdx.x;
    s[t] = pcnt[t << 4];
    __syncthreads();
    for (int off = 1; off < 256; off <<= 1) {
        int v = (t >= off) ? s[t - off] : 0;
        __syncthreads();
        s[t] += v;
        __syncthreads();
    }
    int excl = t ? s[t - 1] : 0;
    pbase[t] = excl;
    ptk[t << 4] = excl;
}

// Scatter rows into compact pair-bucketed list.
__global__ __launch_bounds__(256) void k_scatter(
    const int* __restrict__ rec, int* __restrict__ ptk, int* __restrict__ ridx)
{
    __shared__ int h[256], base_[256];
    const int t = threadIdx.x;
    const int b = blockIdx.x * 256 + t;
    h[t] = 0;
    __syncthreads();
    int pid = rec[b];
    int lo = atomicAdd(&h[pid], 1);
    __syncthreads();
    if (h[t]) base_[t] = atomicAdd(&ptk[t << 4], h[t]);
    __syncthreads();
    ridx[base_[pid] + lo] = b;
}

// Pair-bucket MFMA GEMM: 64 rows x 96 cols x K=512, BOTH experts of the pair,
// full output written directly (no atomics, x gathered once per row).
#define NBCH2 8
__global__ __launch_bounds__(256) void k_gemm(
    const float* __restrict__ x, const unsigned short* __restrict__ Wrb,
    const float* __restrict__ br, const float* __restrict__ Ssum,
    const float4* __restrict__ hdr, float* __restrict__ out,
    const int* __restrict__ pcnt, const int* __restrict__ pbase,
    const int* __restrict__ ridx)
{
    __shared__ __align__(16) unsigned short sA[64 * 72];      // [r][k]
    __shared__ __align__(16) unsigned short sB[2][96 * 72];   // [ex][p][k]
    __shared__ int    s_idx[64];
    __shared__ float4 s_hdr[64];
    __shared__ float  s_br[2][96], s_S[2][96];
    const int pid = blockIdx.x / NBCH2;
    const int cb  = blockIdx.x % NBCH2;
    const int n = pcnt[pid << 4];
    if (n == 0) return;
    const int nch = (n + 63) >> 6;
    if (cb >= nch) return;
    const int base = pbase[pid];
    const int i0 = pid >> 4, i1 = pid & 15;
    const int t = threadIdx.x;
    const int lane = t & 63, wv = t >> 6;
    const int quad = lane >> 4, l16 = lane & 15;
    const int ar = t >> 2, asub = t & 3;
    if (t < 96) {
        s_br[0][t] = (i0 < NEL) ? br[i0 * NP + t] : 0.f;
        s_S [0][t] = (i0 < NEL) ? Ssum[i0 * NP + t] : 0.f;
        s_br[1][t] = (i1 < NEL) ? br[i1 * NP + t] : 0.f;
        s_S [1][t] = (i1 < NEL) ? Ssum[i1 * NP + t] : 0.f;
    }
    const unsigned short* wb0 = Wrb + (size_t)i0 * NP * NL;
    const unsigned short* wb1 = Wrb + (size_t)i1 * NP * NL;

    for (int cc = cb; cc < nch; cc += NBCH2) {
        __syncthreads();                 // protect s_idx/s_hdr from prev epilogue
        if (t < 64) {
            int g = cc * 64 + t;
            bool vld = g < n;
            int row = vld ? ridx[base + g] : -1;
            s_idx[t] = row;
            s_hdr[t] = vld ? hdr[row] : make_float4(0.f, 0.f, 0.f, 0.f);
        }
        __syncthreads();
        f32x4 acc[2][6];
#pragma unroll
        for (int ex = 0; ex < 2; ex++)
#pragma unroll
            for (int j = 0; j < 6; j++) acc[ex][j] = (f32x4){0.f, 0.f, 0.f, 0.f};
        int rr = s_idx[ar]; if (rr < 0) rr = s_idx[0];
        const float* xrow = x + (size_t)rr * NL + asub * 16;

        for (int kb = 0; kb < NL; kb += 64) {
            {   // stage A: row ar, k in [kb+asub*16,+16), f32->bf16
                const float4* src = (const float4*)(xrow + kb);
                unsigned short tmp[16];
#pragma unroll
                for (int i = 0; i < 4; i++) {
                    float4 v = src[i];
                    tmp[i * 4 + 0] = f2bf(v.x); tmp[i * 4 + 1] = f2bf(v.y);
                    tmp[i * 4 + 2] = f2bf(v.z); tmp[i * 4 + 3] = f2bf(v.w);
                }
                unsigned short* dst = sA + ar * 72 + asub * 16;
                *(bf16x8*)dst       = *(bf16x8*)tmp;
                *(bf16x8*)(dst + 8) = *(bf16x8*)(tmp + 8);
            }
#pragma unroll
            for (int it = 0; it < 6; it++) {   // stage B: 2 experts x 96 x 64
                int ex = (it >= 3);
                int fl = t + (it - 3 * ex) * 256;   // 0..767
                int p = fl >> 3, kg = fl & 7;
                const unsigned short* wb = ex ? wb1 : wb0;
                bf16x8 v = *(const bf16x8*)(wb + (size_t)p * NL + kb + kg * 8);
                *(bf16x8*)(&sB[ex][p * 72 + kg * 8]) = v;
            }
            __syncthreads();
#pragma unroll
            for (int ks = 0; ks < 2; ks++) {
                bf16x8 af = *(const bf16x8*)(sA + (wv * 16 + l16) * 72 + ks * 32 + quad * 8);
#pragma unroll
                for (int ex = 0; ex < 2; ex++)
#pragma unroll
                    for (int nt = 0; nt < 6; nt++) {
                        bf16x8 bf = *(const bf16x8*)(&sB[ex][(nt * 16 + l16) * 72 + ks * 32 + quad * 8]);
                        acc[ex][nt] = __builtin_amdgcn_mfma_f32_16x16x32_bf16(af, bf, acc[ex][nt], 0, 0, 0);
                    }
            }
            __syncthreads();
        }
        // epilogue: direct store; branch on expert kind is block-uniform
#pragma unroll
        for (int i = 0; i < 4; i++) {
            int rloc = wv * 16 + quad * 4 + i;
            int row = s_idx[rloc];
            if (row >= 0) {
                float4 h = s_hdr[rloc];
                float mu = h.x, sd = h.y, last = h.z, w0 = h.w, w1 = 1.f - w0;
                float* orow = out + (size_t)row * NP;
#pragma unroll
                for (int nt = 0; nt < 6; nt++) {
                    int p = nt * 16 + l16;
                    float v0 = (i0 < NEL) ? (mu + s_br[0][p] * sd - mu * s_S[0][p] + acc[0][nt][i])
                                          : (i0 == NEL ? mu : last);
                    float v1 = (i1 < NEL) ? (mu + s_br[1][p] * sd - mu * s_S[1][p] + acc[1][nt][i])
                                          : (i1 == NEL ? mu : last);
                    orow[p] = w0 * v0 + w1 * v1;
                }
            }
        }
    }
}

extern "C" void kernel_launch(void* const* d_in, const int* in_sizes, int n_in,
                              void* d_out, int out_size, void* d_ws, size_t ws_size,
                              hipStream_t stream)
{
    const float* x  = (const float*)d_in[0];
    const float* Wg = (const float*)d_in[1];
    const float* bg = (const float*)d_in[2];
    const float* Wr = (const float*)d_in[3];
    const float* br = (const float*)d_in[4];
    float* out = (float*)d_out;
    char* ws = (char*)d_ws;

    int*     pcnt     = (int*)(ws + WS_PCNT);
    int*     ptk      = (int*)(ws + WS_PTK);
    int*     pbase    = (int*)(ws + WS_PBASE);
    int*     flagcnt  = (int*)(ws + WS_FLAGCNT);
    int*     flaglist = (int*)(ws + WS_FLAG);
    float*   Ssum     = (float*)(ws + WS_SSUM);
    float*   WgT      = (float*)(ws + WS_WGT);
    float*   bgT      = (float*)(ws + WS_BGT);
    float2*  twf      = (float2*)(ws + WS_TWF);
    double2* twd      = (double2*)(ws + WS_TWD);
    int*     rec      = (int*)(ws + WS_REC);
    float4*  hdr      = (float4*)(ws + WS_HDR);
    int*     ridx     = (int*)(ws + WS_RIDX);
    unsigned short* Wrb = (unsigned short*)(ws + WS_WRB);

    k_prep<<<dim3(32), dim3(256), 0, stream>>>(Wg, bg, Wr, Ssum, WgT, bgT, twf, twd, pcnt, flagcnt);
    k_cvt<<<dim3(768), dim3(256), 0, stream>>>((const float4*)Wr, (ushort4*)Wrb);
    k_gate<<<dim3(NB_B / 8), dim3(256), 0, stream>>>(x, WgT, bgT, twf, rec, hdr,
                                                     flaglist, flagcnt);
    k_refine<<<dim3(512), dim3(256), 0, stream>>>(x, twd, Wg, bg, rec, hdr,
                                                  flaglist, flagcnt);
    k_count<<<dim3(NB_B / 256), dim3(256), 0, stream>>>(rec, pcnt);
    k_scan<<<dim3(1), dim3(256), 0, stream>>>(pcnt, pbase, ptk);
    k_scatter<<<dim3(NB_B / 256), dim3(256), 0, stream>>>(rec, ptk, ridx);
    k_gemm<<<dim3(256 * NBCH2), dim3(256), 0, stream>>>(x, Wrb, br, Ssum, hdr, out,
                                                        pcnt, pbase, ridx);
}

// Round 6
// 352.762 us; speedup vs baseline: 1.2963x; 1.2963x over previous
//
#include <hip/hip_runtime.h>
#include <math.h>

#define NB_B 65536
#define NL   512
#define NP   96
#define NE   16
#define NEL  14
#define NF   256
#define TEMP_INV (1.0f/0.07f)
#define TAU  1e-5f
#define PI_D 3.14159265358979323846
#define MAXCHK 1280

typedef __attribute__((ext_vector_type(8))) short bf16x8;
typedef __attribute__((ext_vector_type(4))) float f32x4;

// ---------------- workspace layout (bytes) ----------------
// 0        pcnt[256]   padded stride 64B (pair counts)
// 16384    ptk[256]    padded stride 64B (scatter tickets)
// 32768    pbase[256]
// 33792    flagcnt
// 33824    nchk
// 33856    flaglist[65536]
// 296000   Ssum[14*96]
// 301376   WgT[256*16]
// 317760   bgT[16]
// 317824   twf[256]  float2
// 319872   twd[512]  double2
// 328064   rec[65536]  int: pid = i0*16+i1
// 590208   hdr[65536]  float4: mu, sd, last, w0
// 1638784  ridx[65536] int
// 1900928  Wrb[16*96*512] bf16 (experts 14,15 zero-filled)
// 3473792  desc[1280]  int: (pid<<16)|chunk
// total ~3.48 MB

#define WS_PCNT     0
#define WS_PTK      16384
#define WS_PBASE    32768
#define WS_FLAGCNT  33792
#define WS_NCHK     33824
#define WS_FLAG     33856
#define WS_SSUM     296000
#define WS_WGT      301376
#define WS_BGT      317760
#define WS_TWF      317824
#define WS_TWD      319872
#define WS_REC      328064
#define WS_HDR      590208
#define WS_RIDX     1638784
#define WS_WRB      1900928
#define WS_DESC     3473792

__device__ __forceinline__ unsigned short f2bf(float f) {
    unsigned u = __float_as_uint(f);
    unsigned r = (u + 0x7fffu + ((u >> 16) & 1u)) >> 16;
    return (unsigned short)r;
}

__global__ __launch_bounds__(256) void k_prep(
    const float* __restrict__ Wg, const float* __restrict__ bg,
    const float* __restrict__ Wr,
    float* __restrict__ Ssum, float* __restrict__ WgT, float* __restrict__ bgT,
    float2* __restrict__ twf, double2* __restrict__ twd,
    int* __restrict__ pcnt, int* __restrict__ flagcnt)
{
    int g = blockIdx.x * 256 + threadIdx.x;
    if (g < NEL * NP) {
        const float4* w = (const float4*)(Wr + (size_t)g * NL);
        float s = 0.f;
        for (int i = 0; i < NL / 4; i++) { float4 v = w[i]; s += v.x + v.y + v.z + v.w; }
        Ssum[g] = s;
    }
    if (g < NF * NE) {
        int f = g >> 4, e = g & 15;
        WgT[g] = Wg[e * NF + f] * TEMP_INV;
    }
    if (g < NF) {
        double a = -2.0 * PI_D * (double)g / 512.0;
        twf[g] = make_float2((float)cos(a), (float)sin(a));
    }
    if (g < 512) {
        double a = -2.0 * PI_D * (double)g / 512.0;
        twd[g] = make_double2(cos(a), sin(a));
    }
    if (g < 256) pcnt[g << 4] = 0;
    if (g < NE) bgT[g] = bg[g] * TEMP_INV;
    if (g == 300) *flagcnt = 0;
}

// Wr f32 -> bf16 (RNE); experts 14,15 zero-filled. 768 blocks.
__global__ __launch_bounds__(256) void k_cvt(
    const float4* __restrict__ Wr, ushort4* __restrict__ Wrb)
{
    int g = blockIdx.x * 256 + threadIdx.x;
    ushort4 o = make_ushort4(0, 0, 0, 0);
    if (g < NEL * NP * NL / 4) {
        float4 v = Wr[g];
        o.x = f2bf(v.x); o.y = f2bf(v.y); o.z = f2bf(v.z); o.w = f2bf(v.w);
    }
    Wrb[g] = o;
}

// Pack-2 real FFT per wave: rows (2w,2w+1) as z=a+ib, one 512-pt complex FFT,
// conjugate-symmetry split. Emits per-row header (mu,sd,last,w0) + pair id.
__global__ __launch_bounds__(256) void k_gate(
    const float* __restrict__ x,
    const float* __restrict__ WgT, const float* __restrict__ bgT,
    const float2* __restrict__ twf,
    int* __restrict__ rec, float4* __restrict__ hdr,
    int* __restrict__ flaglist, int* __restrict__ flagcnt)
{
    __shared__ float2 s_tw[256];
    __shared__ float2 s_z[4][576];
    __shared__ float  s_g[4][2][16];
    float* s_Iv = (float*)&s_z[0][0];

    const int t = threadIdx.x;
    const int wv = t >> 6, l = t & 63;
    const int b0 = blockIdx.x * 8 + wv * 2;
    s_tw[t] = twf[t];

    const float* xa = x + (size_t)b0 * NL;
    const float* xb = xa + NL;
    float xr[8], xi[8];
#pragma unroll
    for (int k = 0; k < 8; k++) { xr[k] = xa[k * 64 + l]; xi[k] = xb[k * 64 + l]; }

    float sa = 0.f, qa = 0.f, sb = 0.f, qb = 0.f;
#pragma unroll
    for (int k = 0; k < 8; k++) {
        sa += xr[k]; qa += xr[k] * xr[k];
        sb += xi[k]; qb += xi[k] * xi[k];
    }
#pragma unroll
    for (int m = 1; m < 64; m <<= 1) {
        sa += __shfl_xor(sa, m); qa += __shfl_xor(qa, m);
        sb += __shfl_xor(sb, m); qb += __shfl_xor(qb, m);
    }
    const float mu_a = sa * (1.f / 512.f);
    const float sd_a = sqrtf(qa * (1.f / 512.f) - mu_a * mu_a + 1e-5f);
    const float mu_b = sb * (1.f / 512.f);
    const float sd_b = sqrtf(qb * (1.f / 512.f) - mu_b * mu_b + 1e-5f);
    const float last_a = __shfl(xr[7], 63);
    const float last_b = __shfl(xi[7], 63);
#pragma unroll
    for (int k = 0; k < 8; k++) { xr[k] -= mu_a; xi[k] -= mu_b; }
    __syncthreads();

    // ---- DIF FFT (complex), natural in, bit-reversed out ----
#pragma unroll
    for (int k = 0; k < 4; k++) {                       // stage 0: half=256
        float2 w = s_tw[k * 64 + l];
        float ur = xr[k], ui = xi[k], vr = xr[k + 4], vi = xi[k + 4];
        xr[k] = ur + vr; xi[k] = ui + vi;
        float dr = ur - vr, di = ui - vi;
        xr[k + 4] = dr * w.x - di * w.y; xi[k + 4] = dr * w.y + di * w.x;
    }
    {                                                   // stage 1: half=128
        const int kk[4] = {0, 1, 4, 5};
#pragma unroll
        for (int g2 = 0; g2 < 4; g2++) {
            int k = kk[g2];
            float2 w = s_tw[((k & 1) * 64 + l) << 1];
            float ur = xr[k], ui = xi[k], vr = xr[k + 2], vi = xi[k + 2];
            xr[k] = ur + vr; xi[k] = ui + vi;
            float dr = ur - vr, di = ui - vi;
            xr[k + 2] = dr * w.x - di * w.y; xi[k + 2] = dr * w.y + di * w.x;
        }
    }
    {                                                   // stage 2: half=64
        float2 w = s_tw[l << 2];
#pragma unroll
        for (int k = 0; k < 8; k += 2) {
            float ur = xr[k], ui = xi[k], vr = xr[k + 1], vi = xi[k + 1];
            xr[k] = ur + vr; xi[k] = ui + vi;
            float dr = ur - vr, di = ui - vi;
            xr[k + 1] = dr * w.x - di * w.y; xi[k + 1] = dr * w.y + di * w.x;
        }
    }
#pragma unroll
    for (int st = 3; st < 9; st++) {                    // stages 3..8 cross-lane
        const int half = 256 >> st;
        const int tt = (l & (half - 1)) << st;
        float2 w = s_tw[tt];
        const bool up = (l & half) != 0;
        const float cc = up ? w.x : 1.f;
        const float ss = up ? w.y : 0.f;
#pragma unroll
        for (int k = 0; k < 8; k++) {
            float pr = __shfl_xor(xr[k], half);
            float pi = __shfl_xor(xi[k], half);
            float ar = up ? (pr - xr[k]) : (xr[k] + pr);
            float ai = up ? (pi - xi[k]) : (xi[k] + pi);
            xr[k] = ar * cc - ai * ss;
            xi[k] = ar * ss + ai * cc;
        }
    }

#pragma unroll
    for (int k = 0; k < 8; k++) {
        int i = k * 64 + l;
        s_z[wv][i + (i >> 3)] = make_float2(xr[k], xi[k]);
    }
    __syncthreads();

    // conjugate-symmetry split: lane l owns bins f = 4l..4l+3
    float Ia[4], Ib[4];
    float psa = 0.f, psb = 0.f;
#pragma unroll
    for (int j = 0; j < 4; j++) {
        int f = (l << 2) | j;
        int i1_ = (int)(__brev((unsigned)f) >> 23);
        int i2_ = (int)(__brev((unsigned)((512 - f) & 511)) >> 23);
        float2 z1 = s_z[wv][i1_ + (i1_ >> 3)];
        float2 z2 = s_z[wv][i2_ + (i2_ >> 3)];
        float pr_ = z1.x + z2.x, qm = z1.y - z2.y;
        float qp = z1.y + z2.y, pm = z1.x - z2.x;
        Ia[j] = pr_ * pr_ + qm * qm;
        Ib[j] = qp * qp + pm * pm;
        psa += Ia[j]; psb += Ib[j];
    }
#pragma unroll
    for (int m = 1; m < 64; m <<= 1) {
        psa += __shfl_xor(psa, m); psb += __shfl_xor(psb, m);
    }
    if (psa == 0.f) psa = 1.f;
    if (psb == 0.f) psb = 1.f;
    const float inv_a = 1.f / psa, inv_b = 1.f / psb;
    __syncthreads();

    float* myI = s_Iv + wv * 1152;
#pragma unroll
    for (int j = 0; j < 4; j++) {
        int f = (l << 2) | j;
        int fi = f + (f >> 3);
        myI[fi] = Ia[j];
        myI[288 + fi] = Ib[j];
    }
    __syncthreads();

    {
        int e = l >> 2, cq = l & 3;
        float acc_a = 0.f, acc_b = 0.f;
#pragma unroll 4
        for (int j = 0; j < 64; j++) {
            int f = cq * 64 + j;
            int fi = f + (f >> 3);
            float wgv = WgT[f * 16 + e];
            acc_a += myI[fi] * wgv;
            acc_b += myI[288 + fi] * wgv;
        }
        acc_a += __shfl_xor(acc_a, 1); acc_a += __shfl_xor(acc_a, 2);
        acc_b += __shfl_xor(acc_b, 1); acc_b += __shfl_xor(acc_b, 2);
        if (cq == 0) {
            s_g[wv][0][e] = acc_a * inv_a + bgT[e];
            s_g[wv][1][e] = acc_b * inv_b + bgT[e];
        }
    }
    __syncthreads();

#pragma unroll
    for (int r = 0; r < 2; r++) {
        if (l == 0) {
            const float mu = r ? mu_b : mu_a;
            const float sd = r ? sd_b : sd_a;
            const float last = r ? last_b : last_a;
            const int b = b0 + r;
            float b0v = -1e30f, b1v = -1e30f, b2v = -1e30f; int i0 = 0, i1 = 0;
            for (int i = 0; i < 16; i++) {
                float v = s_g[wv][r][i];
                if (v > b0v) { b2v = b1v; b1v = b0v; i1 = i0; b0v = v; i0 = i; }
                else if (v > b1v) { b2v = b1v; b1v = v; i1 = i; }
                else if (v > b2v) { b2v = v; }
            }
            float e1 = expf(b1v - b0v);
            float w0 = 1.f / (1.f + e1);
            rec[b] = i0 * 16 + i1;
            hdr[b] = make_float4(mu, sd, last, w0);
            if (b1v - b2v < TAU) {
                int pos = atomicAdd(flagcnt, 1);
                flaglist[pos] = b;
            }
        }
    }
}

// f64 phasor-DFT refinement for flagged (near-tie) rows: rewrites rec + hdr.w.
__global__ __launch_bounds__(256) void k_refine(
    const float* __restrict__ x, const double2* __restrict__ twd,
    const float* __restrict__ Wg, const float* __restrict__ bg,
    int* __restrict__ rec, float4* __restrict__ hdr,
    const int* __restrict__ flaglist, const int* __restrict__ flagcnt)
{
    __shared__ double s_x[512];
    __shared__ double s_I[256];
    __shared__ double s_red[16];
    __shared__ double s_g[16];
    const int nf = *flagcnt;
    const int t = threadIdx.x;
    const int wid = t >> 6, lane = t & 63;
    for (int fi = blockIdx.x; fi < nf; fi += gridDim.x) {
        const int b = flaglist[fi];
        const float* xp = x + (size_t)b * NL;
        double v0 = (double)xp[t], v1 = (double)xp[t + 256];
        double lsum = v0 + v1;
        for (int m = 1; m < 64; m <<= 1) lsum += __shfl_xor(lsum, m);
        if (lane == 0) s_red[wid] = lsum;
        __syncthreads();
        double mu = (s_red[0] + s_red[1] + s_red[2] + s_red[3]) * (1.0 / 512.0);
        s_x[t] = v0 - mu; s_x[t + 256] = v1 - mu;
        __syncthreads();
        double2 w = twd[t];
        double pr = 1.0, pi = 0.0, cr = 0.0, ci = 0.0;
        for (int n = 0; n < 512; n++) {
            double xv = s_x[n];
            cr += xv * pr; ci += xv * pi;
            double t2 = pr * w.x - pi * w.y;
            pi = pr * w.y + pi * w.x;
            pr = t2;
        }
        double I = cr * cr + ci * ci;
        s_I[t] = I;
        double ls = I;
        for (int m = 1; m < 64; m <<= 1) ls += __shfl_xor(ls, m);
        if (lane == 0) s_red[8 + wid] = ls;
        __syncthreads();
        double stot = s_red[8] + s_red[9] + s_red[10] + s_red[11];
        if (stot == 0.0) stot = 1.0;
        if (t < 16) {
            double acc = 0.0;
            const float* wrow = Wg + t * NF;
            for (int f = 0; f < NF; f++) acc += s_I[f] * (double)wrow[f];
            s_g[t] = (acc / stot + (double)bg[t]) * (1.0 / 0.07);
        }
        __syncthreads();
        if (t == 0) {
            double c0 = -1e300, c1 = -1e300; int j0 = 0, j1 = 0;
            for (int i = 0; i < 16; i++) {
                double v = s_g[i];
                if (v > c0) { c1 = c0; j1 = j0; c0 = v; j0 = i; }
                else if (v > c1) { c1 = v; j1 = i; }
            }
            double e1 = exp(c1 - c0);
            float w0f = (float)(1.0 / (1.0 + e1));
            rec[b] = j0 * 16 + j1;
            ((float*)(hdr + b))[3] = w0f;
        }
        __syncthreads();
    }
}

// Pair histogram: LDS hist -> padded global counters.
__global__ __launch_bounds__(256) void k_count(
    const int* __restrict__ rec, int* __restrict__ pcnt)
{
    __shared__ int h[256];
    const int t = threadIdx.x;
    h[t] = 0;
    __syncthreads();
    atomicAdd(&h[rec[blockIdx.x * 256 + t]], 1);
    __syncthreads();
    if (h[t]) atomicAdd(&pcnt[t << 4], h[t]);
}

// Scan pair counts -> pbase/tickets AND flat chunk descriptors (load balance).
__global__ __launch_bounds__(256) void k_scan(
    const int* __restrict__ pcnt, int* __restrict__ pbase, int* __restrict__ ptk,
    int* __restrict__ desc, int* __restrict__ nchk)
{
    __shared__ int s[256], c[256];
    const int t = threadIdx.x;
    const int n = pcnt[t << 4];
    s[t] = n;
    c[t] = (n + 63) >> 6;          // chunks for this pid
    __syncthreads();
    for (int off = 1; off < 256; off <<= 1) {
        int v1 = (t >= off) ? s[t - off] : 0;
        int v2 = (t >= off) ? c[t - off] : 0;
        __syncthreads();
        s[t] += v1; c[t] += v2;
        __syncthreads();
    }
    int excl = t ? s[t - 1] : 0;
    int cexcl = t ? c[t - 1] : 0;
    pbase[t] = excl;
    ptk[t << 4] = excl;
    int myc = (n + 63) >> 6;
    for (int j = 0; j < myc; j++) desc[cexcl + j] = (t << 16) | j;
    if (t == 255) *nchk = cexcl + myc;
}

// Scatter rows into compact pair-bucketed list.
__global__ __launch_bounds__(256) void k_scatter(
    const int* __restrict__ rec, int* __restrict__ ptk, int* __restrict__ ridx)
{
    __shared__ int h[256], base_[256];
    const int t = threadIdx.x;
    const int b = blockIdx.x * 256 + t;
    h[t] = 0;
    __syncthreads();
    int pid = rec[b];
    int lo = atomicAdd(&h[pid], 1);
    __syncthreads();
    if (h[t]) base_[t] = atomicAdd(&ptk[t << 4], h[t]);
    __syncthreads();
    ridx[base_[pid] + lo] = b;
}

// Pair-bucket MFMA GEMM, flat chunk queue: block = one 64-row chunk of one pid.
// Computes BOTH experts, writes finished rows (no atomics, x gathered once).
__global__ __launch_bounds__(256) void k_gemm(
    const float* __restrict__ x, const unsigned short* __restrict__ Wrb,
    const float* __restrict__ br, const float* __restrict__ Ssum,
    const float4* __restrict__ hdr, float* __restrict__ out,
    const int* __restrict__ pcnt, const int* __restrict__ pbase,
    const int* __restrict__ ridx,
    const int* __restrict__ desc, const int* __restrict__ nchk)
{
    __shared__ __align__(16) unsigned short sA[64 * 72];      // [r][k]
    __shared__ __align__(16) unsigned short sB[2][96 * 72];   // [ex][p][k]
    __shared__ int    s_idx[64];
    __shared__ float4 s_hdr[64];
    __shared__ float  s_br[2][96], s_S[2][96];
    if ((int)blockIdx.x >= *nchk) return;
    const int d = desc[blockIdx.x];
    const int pid = d >> 16, cc = d & 0xffff;
    const int n = pcnt[pid << 4];
    const int base = pbase[pid];
    const int i0 = pid >> 4, i1 = pid & 15;
    const int t = threadIdx.x;
    const int lane = t & 63, wv = t >> 6;
    const int quad = lane >> 4, l16 = lane & 15;
    const int ar = t >> 2, asub = t & 3;
    if (t < 96) {
        s_br[0][t] = (i0 < NEL) ? br[i0 * NP + t] : 0.f;
        s_S [0][t] = (i0 < NEL) ? Ssum[i0 * NP + t] : 0.f;
        s_br[1][t] = (i1 < NEL) ? br[i1 * NP + t] : 0.f;
        s_S [1][t] = (i1 < NEL) ? Ssum[i1 * NP + t] : 0.f;
    }
    if (t < 64) {
        int g = cc * 64 + t;
        bool vld = g < n;
        int row = vld ? ridx[base + g] : -1;
        s_idx[t] = row;
        s_hdr[t] = vld ? hdr[row] : make_float4(0.f, 0.f, 0.f, 0.f);
    }
    const unsigned short* wb0 = Wrb + (size_t)i0 * NP * NL;
    const unsigned short* wb1 = Wrb + (size_t)i1 * NP * NL;
    __syncthreads();

    f32x4 acc[2][6];
#pragma unroll
    for (int ex = 0; ex < 2; ex++)
#pragma unroll
        for (int j = 0; j < 6; j++) acc[ex][j] = (f32x4){0.f, 0.f, 0.f, 0.f};
    int rr = s_idx[ar]; if (rr < 0) rr = s_idx[0];
    const float* xrow = x + (size_t)rr * NL + asub * 16;

    for (int kb = 0; kb < NL; kb += 64) {
        {   // stage A: row ar, k in [kb+asub*16,+16), f32->bf16
            const float4* src = (const float4*)(xrow + kb);
            unsigned short tmp[16];
#pragma unroll
            for (int i = 0; i < 4; i++) {
                float4 v = src[i];
                tmp[i * 4 + 0] = f2bf(v.x); tmp[i * 4 + 1] = f2bf(v.y);
                tmp[i * 4 + 2] = f2bf(v.z); tmp[i * 4 + 3] = f2bf(v.w);
            }
            unsigned short* dst = sA + ar * 72 + asub * 16;
            *(bf16x8*)dst       = *(bf16x8*)tmp;
            *(bf16x8*)(dst + 8) = *(bf16x8*)(tmp + 8);
        }
#pragma unroll
        for (int it = 0; it < 6; it++) {   // stage B: 2 experts x 96 x 64
            int ex = (it >= 3);
            int fl = t + (it - 3 * ex) * 256;
            int p = fl >> 3, kg = fl & 7;
            const unsigned short* wb = ex ? wb1 : wb0;
            bf16x8 v = *(const bf16x8*)(wb + (size_t)p * NL + kb + kg * 8);
            *(bf16x8*)(&sB[ex][p * 72 + kg * 8]) = v;
        }
        __syncthreads();
#pragma unroll
        for (int ks = 0; ks < 2; ks++) {
            bf16x8 af = *(const bf16x8*)(sA + (wv * 16 + l16) * 72 + ks * 32 + quad * 8);
#pragma unroll
            for (int ex = 0; ex < 2; ex++)
#pragma unroll
                for (int nt = 0; nt < 6; nt++) {
                    bf16x8 bf = *(const bf16x8*)(&sB[ex][(nt * 16 + l16) * 72 + ks * 32 + quad * 8]);
                    acc[ex][nt] = __builtin_amdgcn_mfma_f32_16x16x32_bf16(af, bf, acc[ex][nt], 0, 0, 0);
                }
        }
        __syncthreads();
    }
    // epilogue: direct store; expert-kind branches are block-uniform
#pragma unroll
    for (int i = 0; i < 4; i++) {
        int rloc = wv * 16 + quad * 4 + i;
        int row = s_idx[rloc];
        if (row >= 0) {
            float4 h = s_hdr[rloc];
            float mu = h.x, sd = h.y, last = h.z, w0 = h.w, w1 = 1.f - w0;
            float* orow = out + (size_t)row * NP;
#pragma unroll
            for (int nt = 0; nt < 6; nt++) {
                int p = nt * 16 + l16;
                float v0 = (i0 < NEL) ? (mu + s_br[0][p] * sd - mu * s_S[0][p] + acc[0][nt][i])
                                      : (i0 == NEL ? mu : last);
                float v1 = (i1 < NEL) ? (mu + s_br[1][p] * sd - mu * s_S[1][p] + acc[1][nt][i])
                                      : (i1 == NEL ? mu : last);
                orow[p] = w0 * v0 + w1 * v1;
            }
        }
    }
}

extern "C" void kernel_launch(void* const* d_in, const int* in_sizes, int n_in,
                              void* d_out, int out_size, void* d_ws, size_t ws_size,
                              hipStream_t stream)
{
    const float* x  = (const float*)d_in[0];
    const float* Wg = (const float*)d_in[1];
    const float* bg = (const float*)d_in[2];
    const float* Wr = (const float*)d_in[3];
    const float* br = (const float*)d_in[4];
    float* out = (float*)d_out;
    char* ws = (char*)d_ws;

    int*     pcnt     = (int*)(ws + WS_PCNT);
    int*     ptk      = (int*)(ws + WS_PTK);
    int*     pbase    = (int*)(ws + WS_PBASE);
    int*     flagcnt  = (int*)(ws + WS_FLAGCNT);
    int*     nchk     = (int*)(ws + WS_NCHK);
    int*     flaglist = (int*)(ws + WS_FLAG);
    float*   Ssum     = (float*)(ws + WS_SSUM);
    float*   WgT      = (float*)(ws + WS_WGT);
    float*   bgT      = (float*)(ws + WS_BGT);
    float2*  twf      = (float2*)(ws + WS_TWF);
    double2* twd      = (double2*)(ws + WS_TWD);
    int*     rec      = (int*)(ws + WS_REC);
    float4*  hdr      = (float4*)(ws + WS_HDR);
    int*     ridx     = (int*)(ws + WS_RIDX);
    unsigned short* Wrb = (unsigned short*)(ws + WS_WRB);
    int*     desc     = (int*)(ws + WS_DESC);

    k_prep<<<dim3(32), dim3(256), 0, stream>>>(Wg, bg, Wr, Ssum, WgT, bgT, twf, twd, pcnt, flagcnt);
    k_cvt<<<dim3(768), dim3(256), 0, stream>>>((const float4*)Wr, (ushort4*)Wrb);
    k_gate<<<dim3(NB_B / 8), dim3(256), 0, stream>>>(x, WgT, bgT, twf, rec, hdr,
                                                     flaglist, flagcnt);
    k_refine<<<dim3(512), dim3(256), 0, stream>>>(x, twd, Wg, bg, rec, hdr,
                                                  flaglist, flagcnt);
    k_count<<<dim3(NB_B / 256), dim3(256), 0, stream>>>(rec, pcnt);
    k_scan<<<dim3(1), dim3(256), 0, stream>>>(pcnt, pbase, ptk, desc, nchk);
    k_scatter<<<dim3(NB_B / 256), dim3(256), 0, stream>>>(rec, ptk, ridx);
    k_gemm<<<dim3(MAXCHK), dim3(256), 0, stream>>>(x, Wrb, br, Ssum, hdr, out,
                                                   pcnt, pbase, ridx, desc, nchk);
}